// Round 5
// baseline (613.206 us; speedup 1.0000x reference)
//
#include <hip/hip_runtime.h>
#include <hip/hip_fp16.h>

// GCN layer: h = x @ W_conv; conv = D^-1/2 (A+I) D^-1/2 h + b_conv; out = conv @ W_lin + b_lin
// N=50000, E=800000, in_c=256, hid=128.
// h, conv in bf16 row-major. CSR stored as packed u32 records (src u16 | fp16 weight).
//
// R4 post-mortem: 4 rounds of kernel-internal changes all absorbed -> total is
// launch-overhead dominated (~9 dispatches x ~8-10us). This round: 4 dispatches.
//   prep (W transposes + zero deg/bar)
//   mega (P0: GEMM1 || deg/rank, then scan -> finalize -> bucket via software
//         global barrier; 512 blocks @ launch_bounds(256,2) => co-residency
//         guaranteed by construction: LDS 27.6KB -> 5/CU, VGPR<=256 -> >=2/CU)
//   gather
//   GEMM2
// Barrier: monotonic atomic counter + agent-scope acquire spin (same mechanism
// as grid.sync, without the cooperative-launch API that failed in R1).

#define N_NODES 50000
#define N_EDGES 800000
#define IN_C 256
#define HID 128
#define SCAN_BLOCKS ((N_NODES + 255) / 256)   // 196
#define GEMM_MBLK ((N_NODES + 63) / 64)       // 782
#define MEGA_BLOCKS 512
#define GEMM1_BLOCKS 384                      // P0 split: [0,384) GEMM, [384,512) deg
#define LDK 72                                 // 64 + 8 pad (bf16 elems)

// workspace layout (bytes)
#define OFF_H    0UL          // [N][128] bf16 = 12,800,000
#define OFF_CONV 12800000UL   // [N][128] bf16 = 12,800,000
#define OFF_DEG  25600000UL   // 50000 i32
#define OFF_RP   25800000UL   // 50001 i32 (pad to 64)
#define OFF_DINV 26000064UL   // 50000 f32
#define OFF_RANK 26200064UL   // 800000 u16 = 1,600,000
#define OFF_REC  27800064UL   // 800000 u32 = 3,200,000
#define OFF_BSUM 31000064UL   // 256 i32 (bsums[255] = global barrier counter)
#define OFF_WT1  31001088UL   // 128*256 bf16 (W_conv^T)
#define OFF_WT2  31066624UL   // 256*128 bf16 (W_lin^T)

typedef __attribute__((ext_vector_type(8))) short bf16x8;
typedef __attribute__((ext_vector_type(4))) float f32x4;

__device__ __forceinline__ ushort f2bf(float x) {
    unsigned u = __float_as_uint(x);
    u += 0x7fffu + ((u >> 16) & 1u);       // round-to-nearest-even
    return (ushort)(u >> 16);
}

// device-wide barrier: monotonic counter, no reset. Deadlock-free iff all blocks
// co-resident (guaranteed: grid=512, capacity>=2/CU by launch_bounds, ~5/CU actual).
__device__ __forceinline__ void gbar(int* bar, int target) {
    __threadfence();                           // publish this block's writes
    __syncthreads();
    if (threadIdx.x == 0) {
        __hip_atomic_fetch_add(bar, 1, __ATOMIC_ACQ_REL, __HIP_MEMORY_SCOPE_AGENT);
        while (__hip_atomic_load(bar, __ATOMIC_ACQUIRE, __HIP_MEMORY_SCOPE_AGENT) < target)
            __builtin_amdgcn_s_sleep(2);
    }
    __syncthreads();
    __threadfence();
}

// prep: transpose both weight matrices to bf16 [N][K] + zero deg + zero barrier.
__global__ __launch_bounds__(256) void prep_kernel(
    const float* __restrict__ Wc, const float* __restrict__ Wl,
    ushort* __restrict__ wtc, ushort* __restrict__ wtl,
    int* __restrict__ deg, int* __restrict__ bar)
{
    int i = blockIdx.x * 256 + threadIdx.x;          // 256 blocks -> 65536 threads
    if (i < HID * IN_C) {                            // W_conv [256][128] -> [128][256]
        int n = i / IN_C, k = i % IN_C;
        wtc[i] = f2bf(Wc[k * HID + n]);
    } else {                                         // W_lin [128][256] -> [256][128]
        int j = i - HID * IN_C;
        int n = j / HID, k = j % HID;
        wtl[j] = f2bf(Wl[k * IN_C + n]);
    }
    if (i < N_NODES) deg[i] = 0;
    if (i == 0) *bar = 0;
}

// ---------------- register-prefetch GEMM tile body ----------------
// C[M,N] = A[M,KT] @ B[KT,N] (+bias). Tile 64x128, BK=64, KT compile-time.
// Iter k+1's global loads issued BEFORE iter k's barriers/MFMA.
template <int KT, bool A_IS_BF16, bool BF16OUT>
__device__ __forceinline__ void gemm_tile_body(
    const void* __restrict__ Av, const ushort* __restrict__ Bt,
    const float* __restrict__ bias, void* __restrict__ Cv,
    int M, int N, int bx, int by, ushort* As, ushort* Bs)
{
    constexpr int NIT = KT / 64;
    int tid = threadIdx.x;
    int wave = tid >> 6, lane = tid & 63;
    int quad = lane >> 4, l16 = lane & 15;
    int wm0 = (wave >> 1) * 32, wn0 = (wave & 1) * 64;
    int bm = bx * 64, bn = by * 128;

    int arow = tid >> 2, acol = (tid & 3) * 16;   // A: 64 rows x 64 k
    int agrow = bm + arow;
    int brow = tid >> 1, bkk = (tid & 1) * 32;    // B: 128 rows x 64 k

    f32x4 acc[2][4] = {};
    float4 a32[2][4];
    bf16x8 a16[2][2];
    bf16x8 breg[2][4];

    auto issue = [&](int it, int s) {
        int k0 = it * 64;
        if (A_IS_BF16) {
            a16[s][0] = bf16x8{};
            a16[s][1] = bf16x8{};
            if (agrow < M) {
                const ushort* ap = (const ushort*)Av + (size_t)agrow * KT + k0 + acol;
                a16[s][0] = *(const bf16x8*)ap;
                a16[s][1] = *(const bf16x8*)(ap + 8);
            }
        } else {
            a32[s][0] = a32[s][1] = a32[s][2] = a32[s][3] = make_float4(0.f, 0.f, 0.f, 0.f);
            if (agrow < M) {
                const float* ap = (const float*)Av + (size_t)agrow * KT + k0 + acol;
                a32[s][0] = *(const float4*)ap;
                a32[s][1] = *(const float4*)(ap + 4);
                a32[s][2] = *(const float4*)(ap + 8);
                a32[s][3] = *(const float4*)(ap + 12);
            }
        }
        const ushort* bp = Bt + (size_t)(bn + brow) * KT + k0 + bkk;
        breg[s][0] = *(const bf16x8*)bp;
        breg[s][1] = *(const bf16x8*)(bp + 8);
        breg[s][2] = *(const bf16x8*)(bp + 16);
        breg[s][3] = *(const bf16x8*)(bp + 24);
    };

    auto stage = [&](int s) {
        if (A_IS_BF16) {
            *(bf16x8*)&As[arow * LDK + acol]     = a16[s][0];
            *(bf16x8*)&As[arow * LDK + acol + 8] = a16[s][1];
        } else {
            ushort t0[8] = {f2bf(a32[s][0].x), f2bf(a32[s][0].y), f2bf(a32[s][0].z), f2bf(a32[s][0].w),
                            f2bf(a32[s][1].x), f2bf(a32[s][1].y), f2bf(a32[s][1].z), f2bf(a32[s][1].w)};
            ushort t1[8] = {f2bf(a32[s][2].x), f2bf(a32[s][2].y), f2bf(a32[s][2].z), f2bf(a32[s][2].w),
                            f2bf(a32[s][3].x), f2bf(a32[s][3].y), f2bf(a32[s][3].z), f2bf(a32[s][3].w)};
            *(bf16x8*)&As[arow * LDK + acol]     = *(bf16x8*)t0;
            *(bf16x8*)&As[arow * LDK + acol + 8] = *(bf16x8*)t1;
        }
        *(bf16x8*)&Bs[brow * LDK + bkk]      = breg[s][0];
        *(bf16x8*)&Bs[brow * LDK + bkk + 8]  = breg[s][1];
        *(bf16x8*)&Bs[brow * LDK + bkk + 16] = breg[s][2];
        *(bf16x8*)&Bs[brow * LDK + bkk + 24] = breg[s][3];
    };

    issue(0, 0);
    #pragma unroll
    for (int it = 0; it < NIT; ++it) {
        int cur = it & 1;
        if (it + 1 < NIT) issue(it + 1, cur ^ 1);
        if (it > 0) __syncthreads();
        stage(cur);
        __syncthreads();
        bf16x8 af[2][2], bfr[4][2];
        #pragma unroll
        for (int im = 0; im < 2; ++im)
            #pragma unroll
            for (int kh = 0; kh < 2; ++kh)
                af[im][kh] = *(bf16x8*)&As[(wm0 + im * 16 + l16) * LDK + kh * 32 + quad * 8];
        #pragma unroll
        for (int in = 0; in < 4; ++in)
            #pragma unroll
            for (int kh = 0; kh < 2; ++kh)
                bfr[in][kh] = *(bf16x8*)&Bs[(wn0 + in * 16 + l16) * LDK + kh * 32 + quad * 8];
        #pragma unroll
        for (int im = 0; im < 2; ++im)
            #pragma unroll
            for (int in = 0; in < 4; ++in) {
                acc[im][in] = __builtin_amdgcn_mfma_f32_16x16x32_bf16(
                    af[im][0], bfr[in][0], acc[im][in], 0, 0, 0);
                acc[im][in] = __builtin_amdgcn_mfma_f32_16x16x32_bf16(
                    af[im][1], bfr[in][1], acc[im][in], 0, 0, 0);
            }
    }
    __syncthreads();   // LDS safe for reuse by caller after this
    #pragma unroll
    for (int im = 0; im < 2; ++im) {
        #pragma unroll
        for (int in = 0; in < 4; ++in) {
            int col = bn + wn0 + in * 16 + l16;
            float bval = bias ? bias[col] : 0.f;
            #pragma unroll
            for (int r = 0; r < 4; ++r) {
                int grow = bm + wm0 + im * 16 + quad * 4 + r;
                if (grow < M) {
                    float o = acc[im][in][r] + bval;
                    if (BF16OUT)
                        ((ushort*)Cv)[(size_t)grow * N + col] = f2bf(o);
                    else
                        ((float*)Cv)[(size_t)grow * N + col] = o;
                }
            }
        }
    }
}

// standalone GEMM (GEMM2)
template <int KT, bool A_IS_BF16, bool BF16OUT>
__global__ __launch_bounds__(256) void mfma_gemm_kernel(
    const void* __restrict__ Av, const ushort* __restrict__ Bt,
    const float* __restrict__ bias, void* __restrict__ Cv, int M, int N)
{
    __shared__ __align__(16) ushort As[64 * LDK];
    __shared__ __align__(16) ushort Bs[128 * LDK];
    gemm_tile_body<KT, A_IS_BF16, BF16OUT>(Av, Bt, bias, Cv, M, N,
                                           blockIdx.x, blockIdx.y, As, Bs);
}

// ---------------- mega: GEMM1 || deg, then scan -> finalize -> bucket ----------------
__global__ __launch_bounds__(256, 2) void mega_kernel(
    const float* __restrict__ x, const ushort* __restrict__ wt_conv,
    ushort* __restrict__ hb,
    const int* __restrict__ src, const int* __restrict__ dst,
    ushort* __restrict__ rank, int* __restrict__ deg,
    int* __restrict__ row_ptr, int* __restrict__ bsums,
    float* __restrict__ dinv, unsigned* __restrict__ rec, int* __restrict__ bar)
{
    __shared__ __align__(16) ushort smem[64 * LDK + 128 * LDK];   // 27648 B
    int bid = blockIdx.x;
    int tid = threadIdx.x;

    // ---- P0: GEMM1 (h = bf16(x @ W_conv)) on [0,384) || deg/rank on [384,512)
    if (bid < GEMM1_BLOCKS) {
        for (int t = bid; t < GEMM_MBLK; t += GEMM1_BLOCKS)
            gemm_tile_body<IN_C, false, true>(x, wt_conv, nullptr, hb,
                                              N_NODES, HID, t, 0,
                                              smem, smem + 64 * LDK);
    } else {
        const int nb = MEGA_BLOCKS - GEMM1_BLOCKS;   // 128
        for (int e = (bid - GEMM1_BLOCKS) * 256 + tid; e < N_EDGES; e += nb * 256)
            rank[e] = (ushort)atomicAdd(&deg[dst[e]], 1);
    }
    gbar(bar, MEGA_BLOCKS);

    // ---- P1: per-block exclusive scan of deg -> row_ptr, block totals -> bsums
    if (bid < SCAN_BLOCKS) {
        int* tmp = (int*)smem;
        int i = bid * 256 + tid;
        int v = (i < N_NODES) ? deg[i] : 0;
        int orig = v;
        tmp[tid] = v;
        __syncthreads();
        #pragma unroll
        for (int off = 1; off < 256; off <<= 1) {
            int t = (tid >= off) ? tmp[tid - off] : 0;
            __syncthreads();
            tmp[tid] += t;
            __syncthreads();
        }
        if (i < N_NODES) row_ptr[i] = tmp[tid] - orig;
        if (tid == 255) bsums[bid] = tmp[255];
    }
    gbar(bar, 2 * MEGA_BLOCKS);

    // ---- P2: finalize (each block redundantly scans bsums in LDS) + dinv
    if (bid < SCAN_BLOCKS) {
        int* tmp = (int*)smem;
        int* orig = tmp + 256;
        int v = (tid < SCAN_BLOCKS) ? bsums[tid] : 0;
        tmp[tid] = v;
        orig[tid] = v;
        __syncthreads();
        #pragma unroll
        for (int off = 1; off < 256; off <<= 1) {
            int t = (tid >= off) ? tmp[tid - off] : 0;
            __syncthreads();
            tmp[tid] += t;
            __syncthreads();
        }
        int boff = tmp[bid] - orig[bid];
        int i = bid * 256 + tid;
        if (i < N_NODES) {
            row_ptr[i] += boff;
            dinv[i] = rsqrtf((float)(deg[i] + 1));
        }
        if (i == 0) row_ptr[N_NODES] = N_EDGES;
    }
    gbar(bar, 3 * MEGA_BLOCKS);

    // ---- P3: bucket fill (atomic-free, class-filtered: 8 classes x 64 blocks)
    {
        int cls = bid & 7;                       // XCD-aligned
        int blk = bid >> 3;                      // 0..63
        int lo = cls * (N_NODES / 8);            // 6250 per class
        int hi = lo + (N_NODES / 8);
        const int CHUNK = (N_EDGES + 63) / 64;   // 12500
        int e0 = blk * CHUNK;
        int e1 = min(e0 + CHUNK, N_EDGES);
        for (int i = e0 + tid; i < e1; i += 256) {
            int d = dst[i];
            if (d >= lo && d < hi) {
                int s = src[i];
                unsigned r = (unsigned)(ushort)s |
                             ((unsigned)__half_as_ushort(__float2half_rn(dinv[s])) << 16);
                rec[row_ptr[d] + rank[i]] = r;
            }
        }
    }
}

// ---------------- gather ----------------
// convb[d][:] = bf16( di*( sum_in w_s*h[s][:] + di*h[d][:] ) + b_conv )
__device__ __forceinline__ void acc_edge(float4& acc, unsigned r,
                                         const ushort* __restrict__ hb, int c) {
    unsigned s = r & 0xffffu;
    float w = __half2float(__ushort_as_half((ushort)(r >> 16)));
    uint2 v = *(const uint2*)&hb[(size_t)s * HID + c];
    acc.x += w * __uint_as_float(v.x << 16);
    acc.y += w * __uint_as_float(v.x & 0xffff0000u);
    acc.z += w * __uint_as_float(v.y << 16);
    acc.w += w * __uint_as_float(v.y & 0xffff0000u);
}

__global__ __launch_bounds__(256) void gather_kernel(
    const ushort* __restrict__ hb, const int* __restrict__ row_ptr,
    const unsigned* __restrict__ rec, const float* __restrict__ dinv,
    const float* __restrict__ b_conv, ushort* __restrict__ convb, int n)
{
    int wave = threadIdx.x >> 6;
    int lane = threadIdx.x & 63;
    int d = blockIdx.x * 4 + wave;
    if (d >= n) return;
    int half = lane >> 5;
    int l32 = lane & 31;
    int c = l32 << 2;                 // 4 cols per lane

    float4 acc = make_float4(0.f, 0.f, 0.f, 0.f);
    int begin = row_ptr[d], end = row_ptr[d + 1];
    int e = begin + half;             // this half's edges: e, e+2, e+4, ...
    for (; e + 6 < end; e += 8) {
        unsigned r0 = rec[e];
        unsigned r1 = rec[e + 2];
        unsigned r2 = rec[e + 4];
        unsigned r3 = rec[e + 6];
        acc_edge(acc, r0, hb, c);
        acc_edge(acc, r1, hb, c);
        acc_edge(acc, r2, hb, c);
        acc_edge(acc, r3, hb, c);
    }
    for (; e < end; e += 2) {
        unsigned r0 = rec[e];
        acc_edge(acc, r0, hb, c);
    }
    acc.x += __shfl_xor(acc.x, 32);
    acc.y += __shfl_xor(acc.y, 32);
    acc.z += __shfl_xor(acc.z, 32);
    acc.w += __shfl_xor(acc.w, 32);

    if (half == 0) {
        float di = dinv[d];
        uint2 hv = *(const uint2*)&hb[(size_t)d * HID + c];
        acc.x += di * __uint_as_float(hv.x << 16);
        acc.y += di * __uint_as_float(hv.x & 0xffff0000u);
        acc.z += di * __uint_as_float(hv.y << 16);
        acc.w += di * __uint_as_float(hv.y & 0xffff0000u);
        float4 bb = *(const float4*)&b_conv[c];
        float ox = di * acc.x + bb.x;
        float oy = di * acc.y + bb.y;
        float oz = di * acc.z + bb.z;
        float ow = di * acc.w + bb.w;
        uint2 po;
        po.x = ((unsigned)f2bf(oy) << 16) | (unsigned)f2bf(ox);
        po.y = ((unsigned)f2bf(ow) << 16) | (unsigned)f2bf(oz);
        *(uint2*)&convb[(size_t)d * HID + c] = po;
    }
}

extern "C" void kernel_launch(void* const* d_in, const int* in_sizes, int n_in,
                              void* d_out, int out_size, void* d_ws, size_t ws_size,
                              hipStream_t stream) {
    const float* x      = (const float*)d_in[0];
    const int*   ei     = (const int*)d_in[1];
    const float* W_conv = (const float*)d_in[2];
    const float* b_conv = (const float*)d_in[3];
    const float* W_lin  = (const float*)d_in[4];
    const float* b_lin  = (const float*)d_in[5];
    float* out = (float*)d_out;

    char* ws = (char*)d_ws;
    ushort* hb      = (ushort*)(ws + OFF_H);
    ushort* convb   = (ushort*)(ws + OFF_CONV);
    int*    deg     = (int*)(ws + OFF_DEG);
    int*    row_ptr = (int*)(ws + OFF_RP);
    float*  dinv    = (float*)(ws + OFF_DINV);
    ushort* rank    = (ushort*)(ws + OFF_RANK);
    unsigned* rec   = (unsigned*)(ws + OFF_REC);
    int*    bsums   = (int*)(ws + OFF_BSUM);
    ushort* wt_conv = (ushort*)(ws + OFF_WT1);
    ushort* wt_lin  = (ushort*)(ws + OFF_WT2);
    int*    bar     = bsums + 255;               // bsums[255] unused by scan/finalize

    const int* src = ei;
    const int* dst = ei + N_EDGES;

    // K1: W transposes + zero deg + zero barrier
    prep_kernel<<<256, 256, 0, stream>>>(W_conv, W_lin, wt_conv, wt_lin, deg, bar);

    // K2: mega — {GEMM1 || deg/rank} -> scan -> finalize -> bucket
    mega_kernel<<<MEGA_BLOCKS, 256, 0, stream>>>(
        x, wt_conv, hb, src, dst, rank, deg, row_ptr, bsums, dinv, rec, bar);

    // K3: gather
    gather_kernel<<<(N_NODES + 3) / 4, 256, 0, stream>>>(
        hb, row_ptr, rec, dinv, b_conv, convb, N_NODES);

    // K4: out = conv @ W_lin + b_lin
    mfma_gemm_kernel<HID, true, false><<<dim3(GEMM_MBLK, IN_C / 128), 256, 0, stream>>>(
        convb, wt_lin, b_lin, out, N_NODES, IN_C);
}

// Round 6
// 246.625 us; speedup vs baseline: 2.4864x; 2.4864x over previous
//
#include <hip/hip_runtime.h>
#include <hip/hip_fp16.h>

// GCN layer: h = x @ W_conv; conv = D^-1/2 (A+I) D^-1/2 h + b_conv; out = conv @ W_lin + b_lin
// N=50000, E=800000, in_c=256, hid=128.
// h in bf16 row-major. CSR stored as packed u32 records (src u16 | fp16 weight).
//
// R5 post-mortem: software global barrier = 477us (device-scope fences force L2
// writebacks on non-coherent XCDs; WRITE_SIZE +26MB). REVERTED to stream-serial.
// This round: fuse gather+GEMM2 into one barrier-light kernel — each block gathers
// its 64 conv rows into LDS (4 waves x 16 nodes), one __syncthreads, then MFMA
// against wt_lin. Deletes convb round-trip + 1 dispatch; gather latency of some
// blocks overlaps MFMA of others (4 blocks/CU @ 35.8KB LDS).
//
// Pipeline (7 dispatches):
//   memset(deg) -> prep(W transposes + deg/rank) -> scan_blocks -> finalize2
//   -> bucket -> GEMM1 (reg-prefetch) -> gather_gemm2

#define N_NODES 50000
#define N_EDGES 800000
#define IN_C 256
#define HID 128
#define SCAN_BLOCKS ((N_NODES + 255) / 256)   // 196
#define GEMM_MBLK ((N_NODES + 63) / 64)       // 782
#define PREP_BLOCKS 1024
#define BUCKET_BLOCKS 2048                    // 8 classes x 256 chunk-blocks, 0 LDS
#define LDK 72                                 // 64 + 8 pad (bf16 elems)
#define LDK2 136                               // 128 + 8 pad (fused A tile)

// workspace layout (bytes)
#define OFF_H    0UL          // [N][128] bf16 = 12,800,000
#define OFF_CONV 12800000UL   // (unused now)
#define OFF_DEG  25600000UL   // 50000 i32
#define OFF_RP   25800000UL   // 50001 i32 (pad to 64)
#define OFF_DINV 26000064UL   // 50000 f32
#define OFF_RANK 26200064UL   // 800000 u16 = 1,600,000
#define OFF_REC  27800064UL   // 800000 u32 = 3,200,000
#define OFF_BSUM 31000064UL   // 256 i32
#define OFF_WT1  31001088UL   // 128*256 bf16 (W_conv^T)
#define OFF_WT2  31066624UL   // 256*128 bf16 (W_lin^T)

typedef __attribute__((ext_vector_type(8))) short bf16x8;
typedef __attribute__((ext_vector_type(4))) float f32x4;

__device__ __forceinline__ ushort f2bf(float x) {
    unsigned u = __float_as_uint(x);
    u += 0x7fffu + ((u >> 16) & 1u);       // round-to-nearest-even
    return (ushort)(u >> 16);
}

// fused: transpose both weight matrices to bf16 [N][K] + deg count / rank capture.
// deg must be zeroed before this kernel (memset on the same stream).
__global__ __launch_bounds__(256) void prep_kernel(
    const float* __restrict__ Wc, const float* __restrict__ Wl,
    ushort* __restrict__ wtc, ushort* __restrict__ wtl,
    const int* __restrict__ dst, ushort* __restrict__ rank, int* __restrict__ deg)
{
    int i = blockIdx.x * 256 + threadIdx.x;
    if (i < HID * IN_C) {                            // W_conv [256][128] -> [128][256]
        int n = i / IN_C, k = i % IN_C;
        wtc[i] = f2bf(Wc[k * HID + n]);
    } else if (i < 2 * HID * IN_C) {                 // W_lin [128][256] -> [256][128]
        int j = i - HID * IN_C;
        int n = j / HID, k = j % HID;
        wtl[j] = f2bf(Wl[k * IN_C + n]);
    }
    for (int e = i; e < N_EDGES; e += PREP_BLOCKS * 256)
        rank[e] = (ushort)atomicAdd(&deg[dst[e]], 1);
}

__global__ __launch_bounds__(256) void scan_blocks_kernel(
    const int* __restrict__ deg, int* __restrict__ row_ptr,
    int* __restrict__ bsums, int n)
{
    __shared__ int tmp[256];
    int tid = threadIdx.x;
    int i = blockIdx.x * 256 + tid;
    int v = (i < n) ? deg[i] : 0;
    int orig = v;
    tmp[tid] = v;
    __syncthreads();
    #pragma unroll
    for (int off = 1; off < 256; off <<= 1) {
        int t = (tid >= off) ? tmp[tid - off] : 0;
        __syncthreads();
        tmp[tid] += t;
        __syncthreads();
    }
    if (i < n) row_ptr[i] = tmp[tid] - orig;
    if (tid == 255) bsums[blockIdx.x] = tmp[255];
}

// finalize with inlined block-sum scan: every block redundantly scans bsums[0..195]
// in LDS, then applies its own exclusive offset.
__global__ __launch_bounds__(256) void finalize2_kernel(
    const int* __restrict__ deg, int* __restrict__ row_ptr,
    const int* __restrict__ bsums, float* __restrict__ dinv, int n)
{
    __shared__ int tmp[256];
    __shared__ int orig[256];
    int tid = threadIdx.x;
    int v = (tid < SCAN_BLOCKS) ? bsums[tid] : 0;
    tmp[tid] = v;
    orig[tid] = v;
    __syncthreads();
    #pragma unroll
    for (int off = 1; off < 256; off <<= 1) {
        int t = (tid >= off) ? tmp[tid - off] : 0;
        __syncthreads();
        tmp[tid] += t;
        __syncthreads();
    }
    int boff = tmp[blockIdx.x] - orig[blockIdx.x];   // exclusive prefix for this block
    int i = blockIdx.x * 256 + tid;
    if (i < n) {
        row_ptr[i] += boff;
        dinv[i] = rsqrtf((float)(deg[i] + 1));
    }
    if (i == 0) row_ptr[n] = N_EDGES;
}

// CSR fill, atomic-free, XCD-class filtered (blockIdx%8 handles one dst range), 0 LDS.
__global__ __launch_bounds__(256) void bucket_kernel(
    const int* __restrict__ src, const int* __restrict__ dst,
    const ushort* __restrict__ rank, const int* __restrict__ row_ptr,
    const float* __restrict__ dinv, unsigned* __restrict__ rec)
{
    int cls = blockIdx.x & 7;
    int blk = blockIdx.x >> 3;                 // 0..255
    int lo = cls * (N_NODES / 8);              // 6250 per class
    int hi = lo + (N_NODES / 8);
    const int CHUNK = (N_EDGES + 255) / 256;   // 3125
    int e0 = blk * CHUNK;
    int e1 = min(e0 + CHUNK, N_EDGES);
    for (int i = e0 + threadIdx.x; i < e1; i += 256) {
        int d = dst[i];
        if (d >= lo && d < hi) {
            int s = src[i];
            unsigned r = (unsigned)(ushort)s |
                         ((unsigned)__half_as_ushort(__float2half_rn(dinv[s])) << 16);
            rec[row_ptr[d] + rank[i]] = r;
        }
    }
}

// ---------------- register-prefetch MFMA GEMM (GEMM1) ----------------
// C[M,N] = A[M,KT] @ B[KT,N]. Tile 64x128, BK=64, KT compile-time.
// Iter k+1's global loads are issued BEFORE iter k's barriers/MFMA.
template <int KT, bool A_IS_BF16, bool BF16OUT>
__global__ __launch_bounds__(256) void mfma_gemm_kernel(
    const void* __restrict__ Av, const ushort* __restrict__ Bt,
    const float* __restrict__ bias, void* __restrict__ Cv,
    int M, int N)
{
    constexpr int NIT = KT / 64;
    __shared__ __align__(16) ushort As[64 * LDK];
    __shared__ __align__(16) ushort Bs[128 * LDK];
    int tid = threadIdx.x;
    int wave = tid >> 6, lane = tid & 63;
    int quad = lane >> 4, l16 = lane & 15;
    int wm0 = (wave >> 1) * 32, wn0 = (wave & 1) * 64;
    int bm = blockIdx.x * 64, bn = blockIdx.y * 128;

    int arow = tid >> 2, acol = (tid & 3) * 16;   // A: 64 rows x 64 k
    int agrow = bm + arow;
    int brow = tid >> 1, bkk = (tid & 1) * 32;    // B: 128 rows x 64 k

    f32x4 acc[2][4] = {};
    float4 a32[2][4];
    bf16x8 a16[2][2];
    bf16x8 breg[2][4];

    auto issue = [&](int it, int s) {
        int k0 = it * 64;
        if (A_IS_BF16) {
            a16[s][0] = bf16x8{};
            a16[s][1] = bf16x8{};
            if (agrow < M) {
                const ushort* ap = (const ushort*)Av + (size_t)agrow * KT + k0 + acol;
                a16[s][0] = *(const bf16x8*)ap;
                a16[s][1] = *(const bf16x8*)(ap + 8);
            }
        } else {
            a32[s][0] = a32[s][1] = a32[s][2] = a32[s][3] = make_float4(0.f, 0.f, 0.f, 0.f);
            if (agrow < M) {
                const float* ap = (const float*)Av + (size_t)agrow * KT + k0 + acol;
                a32[s][0] = *(const float4*)ap;
                a32[s][1] = *(const float4*)(ap + 4);
                a32[s][2] = *(const float4*)(ap + 8);
                a32[s][3] = *(const float4*)(ap + 12);
            }
        }
        const ushort* bp = Bt + (size_t)(bn + brow) * KT + k0 + bkk;
        breg[s][0] = *(const bf16x8*)bp;
        breg[s][1] = *(const bf16x8*)(bp + 8);
        breg[s][2] = *(const bf16x8*)(bp + 16);
        breg[s][3] = *(const bf16x8*)(bp + 24);
    };

    auto stage = [&](int s) {
        if (A_IS_BF16) {
            *(bf16x8*)&As[arow * LDK + acol]     = a16[s][0];
            *(bf16x8*)&As[arow * LDK + acol + 8] = a16[s][1];
        } else {
            ushort t0[8] = {f2bf(a32[s][0].x), f2bf(a32[s][0].y), f2bf(a32[s][0].z), f2bf(a32[s][0].w),
                            f2bf(a32[s][1].x), f2bf(a32[s][1].y), f2bf(a32[s][1].z), f2bf(a32[s][1].w)};
            ushort t1[8] = {f2bf(a32[s][2].x), f2bf(a32[s][2].y), f2bf(a32[s][2].z), f2bf(a32[s][2].w),
                            f2bf(a32[s][3].x), f2bf(a32[s][3].y), f2bf(a32[s][3].z), f2bf(a32[s][3].w)};
            *(bf16x8*)&As[arow * LDK + acol]     = *(bf16x8*)t0;
            *(bf16x8*)&As[arow * LDK + acol + 8] = *(bf16x8*)t1;
        }
        *(bf16x8*)&Bs[brow * LDK + bkk]      = breg[s][0];
        *(bf16x8*)&Bs[brow * LDK + bkk + 8]  = breg[s][1];
        *(bf16x8*)&Bs[brow * LDK + bkk + 16] = breg[s][2];
        *(bf16x8*)&Bs[brow * LDK + bkk + 24] = breg[s][3];
    };

    issue(0, 0);
    #pragma unroll
    for (int it = 0; it < NIT; ++it) {
        int cur = it & 1;
        if (it + 1 < NIT) issue(it + 1, cur ^ 1);
        if (it > 0) __syncthreads();
        stage(cur);
        __syncthreads();
        bf16x8 af[2][2], bfr[4][2];
        #pragma unroll
        for (int im = 0; im < 2; ++im)
            #pragma unroll
            for (int kh = 0; kh < 2; ++kh)
                af[im][kh] = *(bf16x8*)&As[(wm0 + im * 16 + l16) * LDK + kh * 32 + quad * 8];
        #pragma unroll
        for (int in = 0; in < 4; ++in)
            #pragma unroll
            for (int kh = 0; kh < 2; ++kh)
                bfr[in][kh] = *(bf16x8*)&Bs[(wn0 + in * 16 + l16) * LDK + kh * 32 + quad * 8];
        #pragma unroll
        for (int im = 0; im < 2; ++im)
            #pragma unroll
            for (int in = 0; in < 4; ++in) {
                acc[im][in] = __builtin_amdgcn_mfma_f32_16x16x32_bf16(
                    af[im][0], bfr[in][0], acc[im][in], 0, 0, 0);
                acc[im][in] = __builtin_amdgcn_mfma_f32_16x16x32_bf16(
                    af[im][1], bfr[in][1], acc[im][in], 0, 0, 0);
            }
    }
    #pragma unroll
    for (int im = 0; im < 2; ++im) {
        #pragma unroll
        for (int in = 0; in < 4; ++in) {
            int col = bn + wn0 + in * 16 + l16;
            float bval = bias ? bias[col] : 0.f;
            #pragma unroll
            for (int r = 0; r < 4; ++r) {
                int grow = bm + wm0 + im * 16 + quad * 4 + r;
                if (grow < M) {
                    float o = acc[im][in][r] + bval;
                    if (BF16OUT)
                        ((ushort*)Cv)[(size_t)grow * N + col] = f2bf(o);
                    else
                        ((float*)Cv)[(size_t)grow * N + col] = o;
                }
            }
        }
    }
}

// ---------------- fused gather + GEMM2 ----------------
// Per block (64 nodes): phase A gathers conv rows into LDS As[64][LDK2] (bf16)
// using the tuned wave-per-node edge loop (4 waves x 16 nodes); one barrier;
// phase B computes out[bm:bm+64][0:256] = As @ wt_lin^T + b_lin via MFMA,
// streaming wt_lin per (n-half, k-chunk). No convb round-trip.
__device__ __forceinline__ void acc_edge(float4& acc, unsigned r,
                                         const ushort* __restrict__ hb, int c) {
    unsigned s = r & 0xffffu;
    float w = __half2float(__ushort_as_half((ushort)(r >> 16)));
    uint2 v = *(const uint2*)&hb[(size_t)s * HID + c];
    acc.x += w * __uint_as_float(v.x << 16);
    acc.y += w * __uint_as_float(v.x & 0xffff0000u);
    acc.z += w * __uint_as_float(v.y << 16);
    acc.w += w * __uint_as_float(v.y & 0xffff0000u);
}

__global__ __launch_bounds__(256) void gather_gemm2_kernel(
    const ushort* __restrict__ hb, const int* __restrict__ row_ptr,
    const unsigned* __restrict__ rec, const float* __restrict__ dinv,
    const float* __restrict__ b_conv, const ushort* __restrict__ wt_lin,
    const float* __restrict__ b_lin, float* __restrict__ out)
{
    __shared__ __align__(16) ushort As[64 * LDK2];   // conv tile, 17.4 KB
    __shared__ __align__(16) ushort Bs[128 * LDK];   // wt_lin chunk, 18.4 KB
    int tid = threadIdx.x;
    int wave = tid >> 6, lane = tid & 63;
    int bm = blockIdx.x * 64;
    int half = lane >> 5;
    int l32 = lane & 31;
    int c = l32 << 2;                 // 4 cols per lane

    // ---- phase A: gather 16 nodes per wave into As
    for (int j = 0; j < 16; ++j) {
        int r = wave * 16 + j;
        int d = bm + r;
        float4 acc = make_float4(0.f, 0.f, 0.f, 0.f);
        if (d < N_NODES) {
            int begin = row_ptr[d], end = row_ptr[d + 1];
            int e = begin + half;             // this half's edges: e, e+2, ...
            for (; e + 6 < end; e += 8) {
                unsigned r0 = rec[e];
                unsigned r1 = rec[e + 2];
                unsigned r2 = rec[e + 4];
                unsigned r3 = rec[e + 6];
                acc_edge(acc, r0, hb, c);
                acc_edge(acc, r1, hb, c);
                acc_edge(acc, r2, hb, c);
                acc_edge(acc, r3, hb, c);
            }
            for (; e < end; e += 2) {
                unsigned r0 = rec[e];
                acc_edge(acc, r0, hb, c);
            }
        }
        acc.x += __shfl_xor(acc.x, 32);
        acc.y += __shfl_xor(acc.y, 32);
        acc.z += __shfl_xor(acc.z, 32);
        acc.w += __shfl_xor(acc.w, 32);
        if (half == 0) {
            uint2 po = make_uint2(0u, 0u);
            if (d < N_NODES) {
                float di = dinv[d];
                uint2 hv = *(const uint2*)&hb[(size_t)d * HID + c];
                acc.x += di * __uint_as_float(hv.x << 16);
                acc.y += di * __uint_as_float(hv.x & 0xffff0000u);
                acc.z += di * __uint_as_float(hv.y << 16);
                acc.w += di * __uint_as_float(hv.y & 0xffff0000u);
                float4 bb = *(const float4*)&b_conv[c];
                float ox = di * acc.x + bb.x;
                float oy = di * acc.y + bb.y;
                float oz = di * acc.z + bb.z;
                float ow = di * acc.w + bb.w;
                po.x = ((unsigned)f2bf(oy) << 16) | (unsigned)f2bf(ox);
                po.y = ((unsigned)f2bf(ow) << 16) | (unsigned)f2bf(oz);
            }
            *(uint2*)&As[r * LDK2 + c] = po;
        }
    }
    __syncthreads();

    // ---- phase B: out tile = As @ wt_lin^T (+ b_lin)
    int quad = lane >> 4, l16 = lane & 15;
    int wm0 = (wave >> 1) * 32, wn0 = (wave & 1) * 64;
    int brow = tid >> 1, bkk = (tid & 1) * 32;

    #pragma unroll
    for (int h = 0; h < 2; ++h) {
        int bn = h * 128;
        f32x4 acc2[2][4] = {};
        #pragma unroll
        for (int kq = 0; kq < 2; ++kq) {
            int k0 = kq * 64;
            {   // stage Bs: wt_lin rows [bn..bn+128), cols [k0,k0+64)
                const ushort* bp = wt_lin + (size_t)(bn + brow) * HID + k0 + bkk;
                *(bf16x8*)&Bs[brow * LDK + bkk]      = *(const bf16x8*)bp;
                *(bf16x8*)&Bs[brow * LDK + bkk + 8]  = *(const bf16x8*)(bp + 8);
                *(bf16x8*)&Bs[brow * LDK + bkk + 16] = *(const bf16x8*)(bp + 16);
                *(bf16x8*)&Bs[brow * LDK + bkk + 24] = *(const bf16x8*)(bp + 24);
            }
            __syncthreads();
            bf16x8 af[2][2], bfr[4][2];
            #pragma unroll
            for (int im = 0; im < 2; ++im)
                #pragma unroll
                for (int kh = 0; kh < 2; ++kh)
                    af[im][kh] = *(bf16x8*)&As[(wm0 + im * 16 + l16) * LDK2 + k0 + kh * 32 + quad * 8];
            #pragma unroll
            for (int in = 0; in < 4; ++in)
                #pragma unroll
                for (int kh = 0; kh < 2; ++kh)
                    bfr[in][kh] = *(bf16x8*)&Bs[(wn0 + in * 16 + l16) * LDK + kh * 32 + quad * 8];
            #pragma unroll
            for (int im = 0; im < 2; ++im)
                #pragma unroll
                for (int in = 0; in < 4; ++in) {
                    acc2[im][in] = __builtin_amdgcn_mfma_f32_16x16x32_bf16(
                        af[im][0], bfr[in][0], acc2[im][in], 0, 0, 0);
                    acc2[im][in] = __builtin_amdgcn_mfma_f32_16x16x32_bf16(
                        af[im][1], bfr[in][1], acc2[im][in], 0, 0, 0);
                }
            __syncthreads();
        }
        #pragma unroll
        for (int im = 0; im < 2; ++im) {
            #pragma unroll
            for (int in = 0; in < 4; ++in) {
                int col = bn + wn0 + in * 16 + l16;
                float bval = b_lin[col];
                #pragma unroll
                for (int r = 0; r < 4; ++r) {
                    int grow = bm + wm0 + im * 16 + quad * 4 + r;
                    if (grow < N_NODES)
                        out[(size_t)grow * IN_C + col] = acc2[im][in][r] + bval;
                }
            }
        }
    }
}

extern "C" void kernel_launch(void* const* d_in, const int* in_sizes, int n_in,
                              void* d_out, int out_size, void* d_ws, size_t ws_size,
                              hipStream_t stream) {
    const float* x      = (const float*)d_in[0];
    const int*   ei     = (const int*)d_in[1];
    const float* W_conv = (const float*)d_in[2];
    const float* b_conv = (const float*)d_in[3];
    const float* W_lin  = (const float*)d_in[4];
    const float* b_lin  = (const float*)d_in[5];
    float* out = (float*)d_out;

    char* ws = (char*)d_ws;
    ushort* hb      = (ushort*)(ws + OFF_H);
    int*    deg     = (int*)(ws + OFF_DEG);
    int*    row_ptr = (int*)(ws + OFF_RP);
    float*  dinv    = (float*)(ws + OFF_DINV);
    ushort* rank    = (ushort*)(ws + OFF_RANK);
    unsigned* rec   = (unsigned*)(ws + OFF_REC);
    int*    bsums   = (int*)(ws + OFF_BSUM);
    ushort* wt_conv = (ushort*)(ws + OFF_WT1);
    ushort* wt_lin  = (ushort*)(ws + OFF_WT2);

    const int* src = ei;
    const int* dst = ei + N_EDGES;

    hipMemsetAsync(deg, 0, 200000, stream);

    // K1: W transposes + deg/rank
    prep_kernel<<<PREP_BLOCKS, 256, 0, stream>>>(W_conv, W_lin, wt_conv, wt_lin,
                                                 dst, rank, deg);
    // K2-K3: CSR scan
    scan_blocks_kernel<<<SCAN_BLOCKS, 256, 0, stream>>>(deg, row_ptr, bsums, N_NODES);
    finalize2_kernel<<<SCAN_BLOCKS, 256, 0, stream>>>(deg, row_ptr, bsums, dinv, N_NODES);

    // K4: CSR fill
    bucket_kernel<<<BUCKET_BLOCKS, 256, 0, stream>>>(src, dst, rank, row_ptr, dinv, rec);

    // K5: h = bf16(x @ W_conv) — register-prefetch GEMM
    mfma_gemm_kernel<IN_C, false, true><<<dim3(GEMM_MBLK, HID / 128), 256, 0, stream>>>(
        x, wt_conv, nullptr, hb, N_NODES, HID);

    // K6: fused gather + GEMM2 -> out
    gather_gemm2_kernel<<<GEMM_MBLK, 256, 0, stream>>>(
        hb, row_ptr, rec, dinv, b_conv, wt_lin, b_lin, out);
}

// Round 7
// 229.026 us; speedup vs baseline: 2.6774x; 1.0768x over previous
//
#include <hip/hip_runtime.h>
#include <hip/hip_fp16.h>

// GCN layer: h = x @ W_conv; conv = D^-1/2 (A+I) D^-1/2 h + b_conv; out = conv @ W_lin + b_lin
// N=50000, E=800000, in_c=256, hid=128.
// h, conv in bf16 row-major. CSR stored as packed u32 records (src u16 | fp16 weight).
//
// R6 post-mortem: gather+GEMM2 fusion cost +15us — the fused kernel's 35.8KB LDS
// capped the latency-bound gather phase at 4 blocks/CU (vs 8 standalone). REVERTED
// to the R4 8-dispatch structure. Lesson (with R3): block-range fusion taxes the
// latency-bound role with the compute role's LDS reservation.
//
// This round: gather MLP x2 — unroll 8 edges per 32-lane half (16 h-row loads in
// flight per wave, was 8). VGPR ~100 @ launch_bounds(256,4): 5 waves/SIMD, per-CU
// outstanding loads 20x16=320 vs 32x8=256.
//
// Pipeline (8 dispatches, stream-serial):
//   memset(deg) -> prep(W transposes + deg/rank) -> scan_blocks -> finalize2
//   -> bucket -> GEMM1 (reg-prefetch) -> gather -> GEMM2 (reg-prefetch)

#define N_NODES 50000
#define N_EDGES 800000
#define IN_C 256
#define HID 128
#define SCAN_BLOCKS ((N_NODES + 255) / 256)   // 196
#define GEMM_MBLK ((N_NODES + 63) / 64)       // 782
#define PREP_BLOCKS 1024
#define BUCKET_BLOCKS 2048                    // 8 classes x 256 chunk-blocks, 0 LDS
#define LDK 72                                 // 64 + 8 pad (bf16 elems)

// workspace layout (bytes)
#define OFF_H    0UL          // [N][128] bf16 = 12,800,000
#define OFF_CONV 12800000UL   // [N][128] bf16 = 12,800,000
#define OFF_DEG  25600000UL   // 50000 i32
#define OFF_RP   25800000UL   // 50001 i32 (pad to 64)
#define OFF_DINV 26000064UL   // 50000 f32
#define OFF_RANK 26200064UL   // 800000 u16 = 1,600,000
#define OFF_REC  27800064UL   // 800000 u32 = 3,200,000
#define OFF_BSUM 31000064UL   // 256 i32
#define OFF_WT1  31001088UL   // 128*256 bf16 (W_conv^T)
#define OFF_WT2  31066624UL   // 256*128 bf16 (W_lin^T)

typedef __attribute__((ext_vector_type(8))) short bf16x8;
typedef __attribute__((ext_vector_type(4))) float f32x4;

__device__ __forceinline__ ushort f2bf(float x) {
    unsigned u = __float_as_uint(x);
    u += 0x7fffu + ((u >> 16) & 1u);       // round-to-nearest-even
    return (ushort)(u >> 16);
}

// fused: transpose both weight matrices to bf16 [N][K] + deg count / rank capture.
// deg must be zeroed before this kernel (memset on the same stream).
__global__ __launch_bounds__(256) void prep_kernel(
    const float* __restrict__ Wc, const float* __restrict__ Wl,
    ushort* __restrict__ wtc, ushort* __restrict__ wtl,
    const int* __restrict__ dst, ushort* __restrict__ rank, int* __restrict__ deg)
{
    int i = blockIdx.x * 256 + threadIdx.x;
    if (i < HID * IN_C) {                            // W_conv [256][128] -> [128][256]
        int n = i / IN_C, k = i % IN_C;
        wtc[i] = f2bf(Wc[k * HID + n]);
    } else if (i < 2 * HID * IN_C) {                 // W_lin [128][256] -> [256][128]
        int j = i - HID * IN_C;
        int n = j / HID, k = j % HID;
        wtl[j] = f2bf(Wl[k * IN_C + n]);
    }
    for (int e = i; e < N_EDGES; e += PREP_BLOCKS * 256)
        rank[e] = (ushort)atomicAdd(&deg[dst[e]], 1);
}

__global__ __launch_bounds__(256) void scan_blocks_kernel(
    const int* __restrict__ deg, int* __restrict__ row_ptr,
    int* __restrict__ bsums, int n)
{
    __shared__ int tmp[256];
    int tid = threadIdx.x;
    int i = blockIdx.x * 256 + tid;
    int v = (i < n) ? deg[i] : 0;
    int orig = v;
    tmp[tid] = v;
    __syncthreads();
    #pragma unroll
    for (int off = 1; off < 256; off <<= 1) {
        int t = (tid >= off) ? tmp[tid - off] : 0;
        __syncthreads();
        tmp[tid] += t;
        __syncthreads();
    }
    if (i < n) row_ptr[i] = tmp[tid] - orig;
    if (tid == 255) bsums[blockIdx.x] = tmp[255];
}

// finalize with inlined block-sum scan: every block redundantly scans bsums[0..195]
// in LDS, then applies its own exclusive offset.
__global__ __launch_bounds__(256) void finalize2_kernel(
    const int* __restrict__ deg, int* __restrict__ row_ptr,
    const int* __restrict__ bsums, float* __restrict__ dinv, int n)
{
    __shared__ int tmp[256];
    __shared__ int orig[256];
    int tid = threadIdx.x;
    int v = (tid < SCAN_BLOCKS) ? bsums[tid] : 0;
    tmp[tid] = v;
    orig[tid] = v;
    __syncthreads();
    #pragma unroll
    for (int off = 1; off < 256; off <<= 1) {
        int t = (tid >= off) ? tmp[tid - off] : 0;
        __syncthreads();
        tmp[tid] += t;
        __syncthreads();
    }
    int boff = tmp[blockIdx.x] - orig[blockIdx.x];   // exclusive prefix for this block
    int i = blockIdx.x * 256 + tid;
    if (i < n) {
        row_ptr[i] += boff;
        dinv[i] = rsqrtf((float)(deg[i] + 1));
    }
    if (i == 0) row_ptr[n] = N_EDGES;
}

// CSR fill, atomic-free, XCD-class filtered (blockIdx%8 handles one dst range), 0 LDS.
__global__ __launch_bounds__(256) void bucket_kernel(
    const int* __restrict__ src, const int* __restrict__ dst,
    const ushort* __restrict__ rank, const int* __restrict__ row_ptr,
    const float* __restrict__ dinv, unsigned* __restrict__ rec)
{
    int cls = blockIdx.x & 7;
    int blk = blockIdx.x >> 3;                 // 0..255
    int lo = cls * (N_NODES / 8);              // 6250 per class
    int hi = lo + (N_NODES / 8);
    const int CHUNK = (N_EDGES + 255) / 256;   // 3125
    int e0 = blk * CHUNK;
    int e1 = min(e0 + CHUNK, N_EDGES);
    for (int i = e0 + threadIdx.x; i < e1; i += 256) {
        int d = dst[i];
        if (d >= lo && d < hi) {
            int s = src[i];
            unsigned r = (unsigned)(ushort)s |
                         ((unsigned)__half_as_ushort(__float2half_rn(dinv[s])) << 16);
            rec[row_ptr[d] + rank[i]] = r;
        }
    }
}

// ---------------- register-prefetch MFMA GEMM ----------------
// C[M,N] = A[M,KT] @ B[KT,N] (+bias). Tile 64x128, BK=64, KT compile-time.
// Iter k+1's global loads are issued BEFORE iter k's barriers/MFMA.
template <int KT, bool A_IS_BF16, bool BF16OUT>
__global__ __launch_bounds__(256) void mfma_gemm_kernel(
    const void* __restrict__ Av, const ushort* __restrict__ Bt,
    const float* __restrict__ bias, void* __restrict__ Cv,
    int M, int N)
{
    constexpr int NIT = KT / 64;
    __shared__ __align__(16) ushort As[64 * LDK];
    __shared__ __align__(16) ushort Bs[128 * LDK];
    int tid = threadIdx.x;
    int wave = tid >> 6, lane = tid & 63;
    int quad = lane >> 4, l16 = lane & 15;
    int wm0 = (wave >> 1) * 32, wn0 = (wave & 1) * 64;
    int bm = blockIdx.x * 64, bn = blockIdx.y * 128;

    int arow = tid >> 2, acol = (tid & 3) * 16;   // A: 64 rows x 64 k
    int agrow = bm + arow;
    int brow = tid >> 1, bkk = (tid & 1) * 32;    // B: 128 rows x 64 k

    f32x4 acc[2][4] = {};
    float4 a32[2][4];
    bf16x8 a16[2][2];
    bf16x8 breg[2][4];

    auto issue = [&](int it, int s) {
        int k0 = it * 64;
        if (A_IS_BF16) {
            a16[s][0] = bf16x8{};
            a16[s][1] = bf16x8{};
            if (agrow < M) {
                const ushort* ap = (const ushort*)Av + (size_t)agrow * KT + k0 + acol;
                a16[s][0] = *(const bf16x8*)ap;
                a16[s][1] = *(const bf16x8*)(ap + 8);
            }
        } else {
            a32[s][0] = a32[s][1] = a32[s][2] = a32[s][3] = make_float4(0.f, 0.f, 0.f, 0.f);
            if (agrow < M) {
                const float* ap = (const float*)Av + (size_t)agrow * KT + k0 + acol;
                a32[s][0] = *(const float4*)ap;
                a32[s][1] = *(const float4*)(ap + 4);
                a32[s][2] = *(const float4*)(ap + 8);
                a32[s][3] = *(const float4*)(ap + 12);
            }
        }
        const ushort* bp = Bt + (size_t)(bn + brow) * KT + k0 + bkk;
        breg[s][0] = *(const bf16x8*)bp;
        breg[s][1] = *(const bf16x8*)(bp + 8);
        breg[s][2] = *(const bf16x8*)(bp + 16);
        breg[s][3] = *(const bf16x8*)(bp + 24);
    };

    auto stage = [&](int s) {
        if (A_IS_BF16) {
            *(bf16x8*)&As[arow * LDK + acol]     = a16[s][0];
            *(bf16x8*)&As[arow * LDK + acol + 8] = a16[s][1];
        } else {
            ushort t0[8] = {f2bf(a32[s][0].x), f2bf(a32[s][0].y), f2bf(a32[s][0].z), f2bf(a32[s][0].w),
                            f2bf(a32[s][1].x), f2bf(a32[s][1].y), f2bf(a32[s][1].z), f2bf(a32[s][1].w)};
            ushort t1[8] = {f2bf(a32[s][2].x), f2bf(a32[s][2].y), f2bf(a32[s][2].z), f2bf(a32[s][2].w),
                            f2bf(a32[s][3].x), f2bf(a32[s][3].y), f2bf(a32[s][3].z), f2bf(a32[s][3].w)};
            *(bf16x8*)&As[arow * LDK + acol]     = *(bf16x8*)t0;
            *(bf16x8*)&As[arow * LDK + acol + 8] = *(bf16x8*)t1;
        }
        *(bf16x8*)&Bs[brow * LDK + bkk]      = breg[s][0];
        *(bf16x8*)&Bs[brow * LDK + bkk + 8]  = breg[s][1];
        *(bf16x8*)&Bs[brow * LDK + bkk + 16] = breg[s][2];
        *(bf16x8*)&Bs[brow * LDK + bkk + 24] = breg[s][3];
    };

    issue(0, 0);
    #pragma unroll
    for (int it = 0; it < NIT; ++it) {
        int cur = it & 1;
        if (it + 1 < NIT) issue(it + 1, cur ^ 1);
        if (it > 0) __syncthreads();
        stage(cur);
        __syncthreads();
        bf16x8 af[2][2], bfr[4][2];
        #pragma unroll
        for (int im = 0; im < 2; ++im)
            #pragma unroll
            for (int kh = 0; kh < 2; ++kh)
                af[im][kh] = *(bf16x8*)&As[(wm0 + im * 16 + l16) * LDK + kh * 32 + quad * 8];
        #pragma unroll
        for (int in = 0; in < 4; ++in)
            #pragma unroll
            for (int kh = 0; kh < 2; ++kh)
                bfr[in][kh] = *(bf16x8*)&Bs[(wn0 + in * 16 + l16) * LDK + kh * 32 + quad * 8];
        #pragma unroll
        for (int im = 0; im < 2; ++im)
            #pragma unroll
            for (int in = 0; in < 4; ++in) {
                acc[im][in] = __builtin_amdgcn_mfma_f32_16x16x32_bf16(
                    af[im][0], bfr[in][0], acc[im][in], 0, 0, 0);
                acc[im][in] = __builtin_amdgcn_mfma_f32_16x16x32_bf16(
                    af[im][1], bfr[in][1], acc[im][in], 0, 0, 0);
            }
    }
    #pragma unroll
    for (int im = 0; im < 2; ++im) {
        #pragma unroll
        for (int in = 0; in < 4; ++in) {
            int col = bn + wn0 + in * 16 + l16;
            float bval = bias ? bias[col] : 0.f;
            #pragma unroll
            for (int r = 0; r < 4; ++r) {
                int grow = bm + wm0 + im * 16 + quad * 4 + r;
                if (grow < M) {
                    float o = acc[im][in][r] + bval;
                    if (BF16OUT)
                        ((ushort*)Cv)[(size_t)grow * N + col] = f2bf(o);
                    else
                        ((float*)Cv)[(size_t)grow * N + col] = o;
                }
            }
        }
    }
}

// ---------------- gather ----------------
// convb[d][:] = bf16( di*( sum_in w_s*h[s][:] + di*h[d][:] ) + b_conv )
// wave64 per node; two 32-lane halves process alternate edges.
// Unroll 8 per half -> 16 h-row loads in flight per wave (was 8). VGPR ~100,
// launch_bounds(256,4) caps at 128 (no spill cliff); 5 waves/SIMD.
__device__ __forceinline__ void acc_edge(float4& acc, unsigned r,
                                         const ushort* __restrict__ hb, int c) {
    unsigned s = r & 0xffffu;
    float w = __half2float(__ushort_as_half((ushort)(r >> 16)));
    uint2 v = *(const uint2*)&hb[(size_t)s * HID + c];
    acc.x += w * __uint_as_float(v.x << 16);
    acc.y += w * __uint_as_float(v.x & 0xffff0000u);
    acc.z += w * __uint_as_float(v.y << 16);
    acc.w += w * __uint_as_float(v.y & 0xffff0000u);
}

__global__ __launch_bounds__(256, 4) void gather_kernel(
    const ushort* __restrict__ hb, const int* __restrict__ row_ptr,
    const unsigned* __restrict__ rec, const float* __restrict__ dinv,
    const float* __restrict__ b_conv, ushort* __restrict__ convb, int n)
{
    int wave = threadIdx.x >> 6;
    int lane = threadIdx.x & 63;
    int d = blockIdx.x * 4 + wave;
    if (d >= n) return;
    int half = lane >> 5;
    int l32 = lane & 31;
    int c = l32 << 2;                 // 4 cols per lane

    float4 acc = make_float4(0.f, 0.f, 0.f, 0.f);
    int begin = row_ptr[d], end = row_ptr[d + 1];
    int e = begin + half;             // this half's edges: e, e+2, e+4, ...
    for (; e + 14 < end; e += 16) {   // 8 edges per half per iter
        unsigned r0 = rec[e];
        unsigned r1 = rec[e + 2];
        unsigned r2 = rec[e + 4];
        unsigned r3 = rec[e + 6];
        unsigned r4 = rec[e + 8];
        unsigned r5 = rec[e + 10];
        unsigned r6 = rec[e + 12];
        unsigned r7 = rec[e + 14];
        acc_edge(acc, r0, hb, c);
        acc_edge(acc, r1, hb, c);
        acc_edge(acc, r2, hb, c);
        acc_edge(acc, r3, hb, c);
        acc_edge(acc, r4, hb, c);
        acc_edge(acc, r5, hb, c);
        acc_edge(acc, r6, hb, c);
        acc_edge(acc, r7, hb, c);
    }
    for (; e + 6 < end; e += 8) {
        unsigned r0 = rec[e];
        unsigned r1 = rec[e + 2];
        unsigned r2 = rec[e + 4];
        unsigned r3 = rec[e + 6];
        acc_edge(acc, r0, hb, c);
        acc_edge(acc, r1, hb, c);
        acc_edge(acc, r2, hb, c);
        acc_edge(acc, r3, hb, c);
    }
    for (; e < end; e += 2) {
        unsigned r0 = rec[e];
        acc_edge(acc, r0, hb, c);
    }
    acc.x += __shfl_xor(acc.x, 32);
    acc.y += __shfl_xor(acc.y, 32);
    acc.z += __shfl_xor(acc.z, 32);
    acc.w += __shfl_xor(acc.w, 32);

    if (half == 0) {
        float di = dinv[d];
        uint2 hv = *(const uint2*)&hb[(size_t)d * HID + c];
        acc.x += di * __uint_as_float(hv.x << 16);
        acc.y += di * __uint_as_float(hv.x & 0xffff0000u);
        acc.z += di * __uint_as_float(hv.y << 16);
        acc.w += di * __uint_as_float(hv.y & 0xffff0000u);
        float4 bb = *(const float4*)&b_conv[c];
        float ox = di * acc.x + bb.x;
        float oy = di * acc.y + bb.y;
        float oz = di * acc.z + bb.z;
        float ow = di * acc.w + bb.w;
        uint2 po;
        po.x = ((unsigned)f2bf(oy) << 16) | (unsigned)f2bf(ox);
        po.y = ((unsigned)f2bf(ow) << 16) | (unsigned)f2bf(oz);
        *(uint2*)&convb[(size_t)d * HID + c] = po;
    }
}

extern "C" void kernel_launch(void* const* d_in, const int* in_sizes, int n_in,
                              void* d_out, int out_size, void* d_ws, size_t ws_size,
                              hipStream_t stream) {
    const float* x      = (const float*)d_in[0];
    const int*   ei     = (const int*)d_in[1];
    const float* W_conv = (const float*)d_in[2];
    const float* b_conv = (const float*)d_in[3];
    const float* W_lin  = (const float*)d_in[4];
    const float* b_lin  = (const float*)d_in[5];
    float* out = (float*)d_out;

    char* ws = (char*)d_ws;
    ushort* hb      = (ushort*)(ws + OFF_H);
    ushort* convb   = (ushort*)(ws + OFF_CONV);
    int*    deg     = (int*)(ws + OFF_DEG);
    int*    row_ptr = (int*)(ws + OFF_RP);
    float*  dinv    = (float*)(ws + OFF_DINV);
    ushort* rank    = (ushort*)(ws + OFF_RANK);
    unsigned* rec   = (unsigned*)(ws + OFF_REC);
    int*    bsums   = (int*)(ws + OFF_BSUM);
    ushort* wt_conv = (ushort*)(ws + OFF_WT1);
    ushort* wt_lin  = (ushort*)(ws + OFF_WT2);

    const int* src = ei;
    const int* dst = ei + N_EDGES;

    hipMemsetAsync(deg, 0, 200000, stream);

    // K1: W transposes + deg/rank
    prep_kernel<<<PREP_BLOCKS, 256, 0, stream>>>(W_conv, W_lin, wt_conv, wt_lin,
                                                 dst, rank, deg);
    // K2-K3: CSR scan
    scan_blocks_kernel<<<SCAN_BLOCKS, 256, 0, stream>>>(deg, row_ptr, bsums, N_NODES);
    finalize2_kernel<<<SCAN_BLOCKS, 256, 0, stream>>>(deg, row_ptr, bsums, dinv, N_NODES);

    // K4: CSR fill
    bucket_kernel<<<BUCKET_BLOCKS, 256, 0, stream>>>(src, dst, rank, row_ptr, dinv, rec);

    // K5: h = bf16(x @ W_conv) — register-prefetch GEMM
    mfma_gemm_kernel<IN_C, false, true><<<dim3(GEMM_MBLK, HID / 128), 256, 0, stream>>>(
        x, wt_conv, nullptr, hb, N_NODES, HID);

    // K6: gather (MLP x2)
    gather_kernel<<<(N_NODES + 3) / 4, 256, 0, stream>>>(
        hb, row_ptr, rec, dinv, b_conv, convb, N_NODES);

    // K7: out = conv @ W_lin + b_lin — register-prefetch GEMM
    mfma_gemm_kernel<HID, true, false><<<dim3(GEMM_MBLK, IN_C / 128), 256, 0, stream>>>(
        convb, wt_lin, b_lin, out, N_NODES, IN_C);
}